// Round 2
// baseline (133.039 us; speedup 1.0000x reference)
//
#include <hip/hip_runtime.h>
#include <hip/hip_bf16.h>

#define Mdim 8192
#define Kdim 4096
#define Ndim 4096
#define NCb  64
#define OCCb 4
#define BM   128
#define MPB  2                 // mtiles per block
#define NU   (MPB * OCCb)      // pipeline stages per block = 8

typedef __bf16 bf16x8 __attribute__((ext_vector_type(8)));
typedef float  f32x4  __attribute__((ext_vector_type(4)));

__device__ __forceinline__ unsigned short f2bf(float f) {
    unsigned u = __builtin_bit_cast(unsigned, f);
    u += 0x7fffu + ((u >> 16) & 1u);          // round-to-nearest-even
    return (unsigned short)(u >> 16);
}

__global__ __launch_bounds__(256) void sparse_linear_kernel(
    const float* __restrict__ A, const float* __restrict__ Bd,
    const int* __restrict__ rowi, const int* __restrict__ di,
    float* __restrict__ C)
{
    // B: all 4 nonzero blocks of column c, transposed [s][n][k] bf16, swizzled. 32 KB.
    __shared__ __align__(16) unsigned short Bt[OCCb * 64 * 64];
    // A: double-buffered [2][128][64] bf16, swizzled. 32 KB.
    __shared__ __align__(16) unsigned short Ab[2 * BM * 64];
    char* BtB = (char*)Bt;
    char* AbB = (char*)Ab;

    // XCD-chunked swizzle: 2048 blocks, 8 XCDs, 256 logical per XCD.
    // logical = c*32 + grp  -> each XCD owns 8 consecutive columns (B L2-resident).
    const int bid = blockIdx.x;
    const int w_  = (bid & 7) * 256 + (bid >> 3);
    const int c   = w_ >> 5;          // 0..63
    const int grp = w_ & 31;          // 0..31 (mtiles grp*2, grp*2+1)

    const int t    = threadIdx.x;
    const int lane = t & 63;
    const int w    = t >> 6;
    const int wr   = w >> 1, wc = w & 1;   // 2x2 waves, wave tile 64x32

    int rs[OCCb], ds[OCCb];
    #pragma unroll
    for (int s = 0; s < OCCb; ++s) {
        rs[s] = rowi[s * NCb + c];
        ds[s] = di[s * NCb + c];
    }

    // ---- issue A stage 0 (T14: loads in flight across B staging) ----
    float4 av[8];
    {
        const float* Ag = A + (long)(grp * MPB) * BM * Kdim + (long)rs[0] * 64
                        + (long)(t >> 4) * Kdim + (t & 15) * 4;
        #pragma unroll
        for (int i = 0; i < 8; ++i) av[i] = *(const float4*)(Ag + (long)i * 16 * Kdim);
    }

    // ---- stage B once: thread t owns column n = t&63 of s-block t>>6 ----
    {
        const int n  = t & 63;
        const int sb = t >> 6;
        const float* Bg = Bd + (long)ds[sb] * 64 + n;   // col n of block; row stride 16384
        char* dst = BtB + sb * 8192 + n * 128;
        const int sw = (n & 7) << 4;
        #pragma unroll
        for (int k4 = 0; k4 < 16; ++k4) {
            ushort4 u;
            u.x = f2bf(Bg[(long)(4 * k4 + 0) * 16384]);
            u.y = f2bf(Bg[(long)(4 * k4 + 1) * 16384]);
            u.z = f2bf(Bg[(long)(4 * k4 + 2) * 16384]);
            u.w = f2bf(Bg[(long)(4 * k4 + 3) * 16384]);
            *(ushort4*)(dst + ((8 * k4) ^ sw)) = u;
        }
    }
    __syncthreads();   // B visible

    // ---- convert + write A stage 0 into buf 0 ----
    {
        const int sw = ((t >> 4) & 7) << 4;
        char* dst = AbB + (t >> 4) * 128 + ((8 * (t & 15)) ^ sw);
        #pragma unroll
        for (int i = 0; i < 8; ++i) {
            ushort4 p;
            p.x = f2bf(av[i].x); p.y = f2bf(av[i].y);
            p.z = f2bf(av[i].z); p.w = f2bf(av[i].w);
            *(ushort4*)(dst + i * 2048) = p;   // row = i*16 + (t>>4)
        }
    }
    __syncthreads();

    f32x4 acc[4][2];
    #pragma unroll
    for (int m = 0; m < 4; ++m)
        #pragma unroll
        for (int n = 0; n < 2; ++n) acc[m][n] = f32x4{0.f, 0.f, 0.f, 0.f};

    for (int u = 0; u < NU; ++u) {
        // issue next stage's global loads (latency hidden under this stage's MFMA)
        if (u + 1 < NU) {
            const int mt = (u + 1) >> 2, s = (u + 1) & 3;
            const float* Ag = A + (long)(grp * MPB + mt) * BM * Kdim + (long)rs[s] * 64
                            + (long)(t >> 4) * Kdim + (t & 15) * 4;
            #pragma unroll
            for (int i = 0; i < 8; ++i) av[i] = *(const float4*)(Ag + (long)i * 16 * Kdim);
        }

        // ---- compute stage u from Ab[u&1] and Bt[s] ----
        {
            const int s = u & 3;
            const char* abase = AbB + (u & 1) * 16384;
            const char* bbase = BtB + s * 8192;
            const int swl = (lane & 7) << 4;
            #pragma unroll
            for (int kb = 0; kb < 2; ++kb) {
                const int kbyte = kb * 64 + (lane >> 4) * 16;
                bf16x8 af[4], bfv[2];
                #pragma unroll
                for (int m = 0; m < 4; ++m) {
                    const int row = wr * 64 + m * 16 + (lane & 15);
                    af[m] = *(const bf16x8*)(abase + row * 128 + (kbyte ^ swl));
                }
                #pragma unroll
                for (int n = 0; n < 2; ++n) {
                    const int nr = wc * 32 + n * 16 + (lane & 15);
                    bfv[n] = *(const bf16x8*)(bbase + nr * 128 + (kbyte ^ swl));
                }
                #pragma unroll
                for (int m = 0; m < 4; ++m)
                    #pragma unroll
                    for (int n = 0; n < 2; ++n)
                        acc[m][n] = __builtin_amdgcn_mfma_f32_16x16x32_bf16(
                            af[m], bfv[n], acc[m][n], 0, 0, 0);
            }
        }

        // ---- convert + write next stage (loads have had a full compute to land) ----
        if (u + 1 < NU) {
            const int sw = ((t >> 4) & 7) << 4;
            char* dst = AbB + ((u + 1) & 1) * 16384 + (t >> 4) * 128 + ((8 * (t & 15)) ^ sw);
            #pragma unroll
            for (int i = 0; i < 8; ++i) {
                ushort4 p;
                p.x = f2bf(av[i].x); p.y = f2bf(av[i].y);
                p.z = f2bf(av[i].z); p.w = f2bf(av[i].w);
                *(ushort4*)(dst + i * 2048) = p;
            }
        }

        // ---- C write at end of each mtile (nontemporal: don't evict A/B) ----
        if ((u & 3) == 3) {
            const int mt = u >> 2;
            const long m0 = (long)(grp * MPB + mt) * BM;
            #pragma unroll
            for (int m = 0; m < 4; ++m)
                #pragma unroll
                for (int n = 0; n < 2; ++n) {
                    const long row = m0 + wr * 64 + m * 16 + (lane >> 4) * 4;
                    const long col = (long)c * 64 + wc * 32 + n * 16 + (lane & 15);
                    #pragma unroll
                    for (int v = 0; v < 4; ++v)
                        __builtin_nontemporal_store(acc[m][n][v], &C[(row + v) * Ndim + col]);
                    acc[m][n] = f32x4{0.f, 0.f, 0.f, 0.f};
                }
        }

        __syncthreads();   // write(u+1) visible; everyone done reading Ab[u&1]
    }
}

extern "C" void kernel_launch(void* const* d_in, const int* in_sizes, int n_in,
                              void* d_out, int out_size, void* d_ws, size_t ws_size,
                              hipStream_t stream) {
    const float* A    = (const float*)d_in[0];
    const float* Bd   = (const float*)d_in[1];
    const int*   rowi = (const int*)d_in[2];
    const int*   di   = (const int*)d_in[3];
    float*       C    = (float*)d_out;

    dim3 grid(64 * 32);   // NC=64 columns x 32 mtile-groups (MPB=2), XCD-swizzled in-kernel
    dim3 block(256);
    hipLaunchKernelGGL(sparse_linear_kernel, grid, block, 0, stream,
                       A, Bd, rowi, di, C);
}

// Round 3
// 78.917 us; speedup vs baseline: 1.6858x; 1.6858x over previous
//
#include <hip/hip_runtime.h>
#include <hip/hip_bf16.h>

typedef __bf16 bf16x8 __attribute__((ext_vector_type(8)));
typedef float  f32x4  __attribute__((ext_vector_type(4)));

__device__ __forceinline__ unsigned short f2bf(float f) {
    unsigned u = __builtin_bit_cast(unsigned, f);
    u += 0x7fffu + ((u >> 16) & 1u);          // round-to-nearest-even
    return (unsigned short)(u >> 16);
}

// Block: 256 threads = 4 waves. Each block owns one output column-block c and
// 256 M-rows (each wave 64 rows, 4 m-tiles of 16). B (4 nonzero 64x64 blocks of
// column c) is staged ONCE into LDS (bf16, [s][n][k] transposed, XOR-swizzled);
// A fragments are loaded DIRECTLY from global per MFMA (8 contiguous fp32 per
// lane -> 2x float4), converted to bf16 in-register. One barrier total; the
// main loop is barrier-free so waves slip freely and hide HBM latency.
__global__ __launch_bounds__(256) void sparse_linear_kernel(
    const float* __restrict__ A, const float* __restrict__ Bd,
    const int* __restrict__ rowi, const int* __restrict__ di,
    float* __restrict__ C)
{
    __shared__ __align__(16) unsigned short Bt[4 * 64 * 64];   // 32 KB
    char* BtB = (char*)Bt;

    const int bid = blockIdx.x;
    const int c   = bid & 63;          // m-chunk-major: one m-slice's 64 columns run together
    const int mch = bid >> 6;          // 0..31
    const int t    = threadIdx.x;
    const int lane = t & 63;
    const int w    = t >> 6;

    int rs[4], ds[4];
    #pragma unroll
    for (int s = 0; s < 4; ++s) {
        rs[s] = rowi[s * 64 + c];
        ds[s] = di[s * 64 + c];
    }

    // ---- stage B once: wave sb stages block s=sb; lane n owns column n ----
    {
        const int n  = t & 63;
        const int sb = t >> 6;
        const float* Bg = Bd + (long)ds[sb] * 64 + n;     // row stride = BN*TB = 16384
        char* dst = BtB + sb * 8192 + n * 128;
        const int sw = (n & 7) << 4;
        #pragma unroll
        for (int k4 = 0; k4 < 16; ++k4) {
            ushort4 u;
            u.x = f2bf(Bg[(long)(4 * k4 + 0) * 16384]);
            u.y = f2bf(Bg[(long)(4 * k4 + 1) * 16384]);
            u.z = f2bf(Bg[(long)(4 * k4 + 2) * 16384]);
            u.w = f2bf(Bg[(long)(4 * k4 + 3) * 16384]);
            *(ushort4*)(dst + ((8 * k4) ^ sw)) = u;
        }
    }
    __syncthreads();   // the only barrier in the kernel

    const long mbase  = (long)mch * 256 + w * 64;
    const int  kbyte0 = (lane >> 4) * 16;   // lane's 16B slot within a 128B k-row

    for (int mt = 0; mt < 4; ++mt) {
        const long  row = mbase + mt * 16 + (lane & 15);
        const float* Ar = A + row * 4096 + (lane >> 4) * 8;

        // burst-issue ALL 16 independent A loads for this m-tile (8 KB/wave in flight)
        float4 av[16];
        #pragma unroll
        for (int s = 0; s < 4; ++s) {
            const float* Ak = Ar + rs[s] * 64;
            av[s * 4 + 0] = *(const float4*)(Ak);
            av[s * 4 + 1] = *(const float4*)(Ak + 4);
            av[s * 4 + 2] = *(const float4*)(Ak + 32);
            av[s * 4 + 3] = *(const float4*)(Ak + 36);
        }

        f32x4 acc[4];
        #pragma unroll
        for (int n2 = 0; n2 < 4; ++n2) acc[n2] = f32x4{0.f, 0.f, 0.f, 0.f};

        #pragma unroll
        for (int s = 0; s < 4; ++s) {
            const char* bbase = BtB + s * 8192;
            #pragma unroll
            for (int kh = 0; kh < 2; ++kh) {
                const float4 a0 = av[s * 4 + kh * 2];
                const float4 a1 = av[s * 4 + kh * 2 + 1];
                union { bf16x8 v; unsigned short u[8]; } af;
                af.u[0] = f2bf(a0.x); af.u[1] = f2bf(a0.y);
                af.u[2] = f2bf(a0.z); af.u[3] = f2bf(a0.w);
                af.u[4] = f2bf(a1.x); af.u[5] = f2bf(a1.y);
                af.u[6] = f2bf(a1.z); af.u[7] = f2bf(a1.w);
                const int kb = kh * 64 + kbyte0;
                #pragma unroll
                for (int n2 = 0; n2 < 4; ++n2) {
                    const int nr = n2 * 16 + (lane & 15);
                    bf16x8 bf = *(const bf16x8*)(bbase + nr * 128 + (kb ^ ((nr & 7) << 4)));
                    acc[n2] = __builtin_amdgcn_mfma_f32_16x16x32_bf16(af.v, bf, acc[n2], 0, 0, 0);
                }
            }
        }

        // ---- C write (NT: don't let the C stream evict A from L2/L3) ----
        const long crow0 = mbase + mt * 16 + (lane >> 4) * 4;
        const long col0  = (long)c * 64 + (lane & 15);
        #pragma unroll
        for (int n2 = 0; n2 < 4; ++n2)
            #pragma unroll
            for (int v = 0; v < 4; ++v)
                __builtin_nontemporal_store(acc[n2][v], &C[(crow0 + v) * 4096 + col0 + n2 * 16]);
    }
}

extern "C" void kernel_launch(void* const* d_in, const int* in_sizes, int n_in,
                              void* d_out, int out_size, void* d_ws, size_t ws_size,
                              hipStream_t stream) {
    const float* A    = (const float*)d_in[0];
    const float* Bd   = (const float*)d_in[1];
    const int*   rowi = (const int*)d_in[2];
    const int*   di   = (const int*)d_in[3];
    float*       C    = (float*)d_out;

    dim3 grid(64 * 32);   // 32 m-chunks x 64 columns, m-chunk-major
    dim3 block(256);
    hipLaunchKernelGGL(sparse_linear_kernel, grid, block, 0, stream,
                       A, Bd, rowi, di, C);
}

// Round 4
// 74.569 us; speedup vs baseline: 1.7841x; 1.0583x over previous
//
#include <hip/hip_runtime.h>
#include <hip/hip_bf16.h>

typedef __bf16 bf16x8 __attribute__((ext_vector_type(8)));
typedef float  f32x4  __attribute__((ext_vector_type(4)));

// Block: 256 threads = 4 waves, one output column-block c, 256 M-rows (64/wave).
// B (4 nonzero 64x64 blocks of column c) staged ONCE to LDS (bf16, [s][n][k]
// transposed, XOR-swizzled); A fragments loaded directly from global, converted
// in-register. Main loop is a flattened 16-step (mt x s) software pipeline with
// prefetch depth 4: each step converts slot (step&3) then re-issues that slot's
// 4 float4 loads for step+4, so the wave issues memory continuously instead of
// bursting once per m-tile. One barrier total.
__global__ __launch_bounds__(256) void sparse_linear_kernel(
    const float* __restrict__ A, const float* __restrict__ Bd,
    const int* __restrict__ rowi, const int* __restrict__ di,
    float* __restrict__ C)
{
    __shared__ __align__(16) unsigned short Bt[4 * 64 * 64];   // 32 KB
    char* BtB = (char*)Bt;

    const int bid = blockIdx.x;
    const int c   = bid & 63;          // m-chunk-major: 4 A-panel sharers run together
    const int mch = bid >> 6;          // 0..31
    const int t    = threadIdx.x;
    const int lane = t & 63;
    const int w    = t >> 6;

    int rs[4], ds[4];
    #pragma unroll
    for (int s = 0; s < 4; ++s) {
        rs[s] = rowi[s * 64 + c];
        ds[s] = di[s * 64 + c];
    }
    int koff[4];
    #pragma unroll
    for (int s = 0; s < 4; ++s) koff[s] = rs[s] * 64;

    const long mbase = (long)mch * 256 + w * 64;
    const float* Abase = A + (mbase + (lane & 15)) * 4096 + (lane >> 4) * 8;

    // ---- prologue: prefetch steps 0..3 (mt=0, s=0..3) -> 16 float4 in flight ----
    float4 pf[4][4];
    #pragma unroll
    for (int st = 0; st < 4; ++st) {
        const float* p = Abase + koff[st];
        pf[st][0] = *(const float4*)(p);
        pf[st][1] = *(const float4*)(p + 4);
        pf[st][2] = *(const float4*)(p + 32);
        pf[st][3] = *(const float4*)(p + 36);
    }

    // ---- stage B once: wave sb stages block sb; lane n owns column n ----
    {
        const int n  = t & 63;
        const int sb = t >> 6;
        const float* Bg = Bd + (long)ds[sb] * 64 + n;   // row stride = BN*TB = 16384
        char* dst = BtB + sb * 8192 + n * 128;
        const int sw = (n & 7) << 4;
        #pragma unroll
        for (int k4 = 0; k4 < 16; ++k4) {
            union { ushort4 u; __bf16 e[4]; } pk;
            pk.e[0] = (__bf16)Bg[(long)(4 * k4 + 0) * 16384];
            pk.e[1] = (__bf16)Bg[(long)(4 * k4 + 1) * 16384];
            pk.e[2] = (__bf16)Bg[(long)(4 * k4 + 2) * 16384];
            pk.e[3] = (__bf16)Bg[(long)(4 * k4 + 3) * 16384];
            *(ushort4*)(dst + ((8 * k4) ^ sw)) = pk.u;
        }
    }
    __syncthreads();   // the only barrier

    f32x4 acc[4];
    #pragma unroll
    for (int n2 = 0; n2 < 4; ++n2) acc[n2] = f32x4{0.f, 0.f, 0.f, 0.f};

    #pragma unroll
    for (int step = 0; step < 16; ++step) {
        const int mt = step >> 2, s = step & 3, slot = step & 3;

        // convert this step's A fragments (consumes pf[slot], freeing it)
        union { bf16x8 v; __bf16 e[8]; } af0, af1;
        {
            const float4 a0 = pf[slot][0], a1 = pf[slot][1];
            const float4 a2 = pf[slot][2], a3 = pf[slot][3];
            af0.e[0] = (__bf16)a0.x; af0.e[1] = (__bf16)a0.y;
            af0.e[2] = (__bf16)a0.z; af0.e[3] = (__bf16)a0.w;
            af0.e[4] = (__bf16)a1.x; af0.e[5] = (__bf16)a1.y;
            af0.e[6] = (__bf16)a1.z; af0.e[7] = (__bf16)a1.w;
            af1.e[0] = (__bf16)a2.x; af1.e[1] = (__bf16)a2.y;
            af1.e[2] = (__bf16)a2.z; af1.e[3] = (__bf16)a2.w;
            af1.e[4] = (__bf16)a3.x; af1.e[5] = (__bf16)a3.y;
            af1.e[6] = (__bf16)a3.z; af1.e[7] = (__bf16)a3.w;
        }

        // re-issue the freed slot for step+4 (WAR on pf[slot] orders this after the converts)
        if (step + 4 < 16) {
            const int mt2 = (step + 4) >> 2, s2 = (step + 4) & 3;
            const float* p = Abase + (long)mt2 * (16 * 4096) + koff[s2];
            pf[slot][0] = *(const float4*)(p);
            pf[slot][1] = *(const float4*)(p + 4);
            pf[slot][2] = *(const float4*)(p + 32);
            pf[slot][3] = *(const float4*)(p + 36);
        }

        // 8 MFMAs for this (mt, s)
        const char* bbase = BtB + s * 8192;
        __builtin_amdgcn_s_setprio(1);
        #pragma unroll
        for (int kh = 0; kh < 2; ++kh) {
            const bf16x8 afv = kh ? af1.v : af0.v;
            const int kb = kh * 64 + (lane >> 4) * 16;
            #pragma unroll
            for (int n2 = 0; n2 < 4; ++n2) {
                const int nr = n2 * 16 + (lane & 15);
                bf16x8 bf = *(const bf16x8*)(bbase + nr * 128 + (kb ^ ((nr & 7) << 4)));
                acc[n2] = __builtin_amdgcn_mfma_f32_16x16x32_bf16(afv, bf, acc[n2], 0, 0, 0);
            }
        }
        __builtin_amdgcn_s_setprio(0);

        // C write at end of each m-tile (NT: keep A/B resident in L2/L3)
        if (s == 3) {
            const long crow0 = mbase + mt * 16 + (lane >> 4) * 4;
            const long col0  = (long)c * 64 + (lane & 15);
            #pragma unroll
            for (int n2 = 0; n2 < 4; ++n2) {
                #pragma unroll
                for (int v = 0; v < 4; ++v)
                    __builtin_nontemporal_store(acc[n2][v],
                        &C[(crow0 + v) * 4096 + col0 + n2 * 16]);
                acc[n2] = f32x4{0.f, 0.f, 0.f, 0.f};
            }
        }
    }
}

extern "C" void kernel_launch(void* const* d_in, const int* in_sizes, int n_in,
                              void* d_out, int out_size, void* d_ws, size_t ws_size,
                              hipStream_t stream) {
    const float* A    = (const float*)d_in[0];
    const float* Bd   = (const float*)d_in[1];
    const int*   rowi = (const int*)d_in[2];
    const int*   di   = (const int*)d_in[3];
    float*       C    = (float*)d_out;

    dim3 grid(64 * 32);   // 32 m-chunks x 64 columns, m-chunk-major
    dim3 block(256);
    hipLaunchKernelGGL(sparse_linear_kernel, grid, block, 0, stream,
                       A, Bd, rowi, di, C);
}